// Round 3
// baseline (568.210 us; speedup 1.0000x reference)
//
#include <hip/hip_runtime.h>
#include <hip/hip_bf16.h>

typedef short short8 __attribute__((ext_vector_type(8)));
typedef float floatx4 __attribute__((ext_vector_type(4)));

#define XP 328   // X LDS pitch (bf16): 656 B rows (16B-aligned); lane row-stride ≡ 4 mod 32 words -> 2-way only
#define HP 168   // h1/ht LDS pitch: 336 B rows (16B-aligned)

__device__ __forceinline__ unsigned short f2bf(float f) {
    __hip_bfloat16 h = __float2bfloat16(f);
    return __builtin_bit_cast(unsigned short, h);
}
__device__ __forceinline__ float bf2f(unsigned short s) {
    __hip_bfloat16 h = __builtin_bit_cast(__hip_bfloat16, s);
    return __bfloat162float(h);
}

// Pack Wc = [w1; wt] (320x320) into B-fragment order for mfma_f32_16x16x32_bf16.
// elem j of lane l for (t,kb): n = t*16+(l&15), k = kb*32+(l>>4)*8+j; flat (((t*10+kb)*64+l)*8+j)
__global__ void pack_wc(const float* __restrict__ w1, const float* __restrict__ wt,
                        unsigned short* __restrict__ dst) {
    int i = blockIdx.x * 256 + threadIdx.x;
    if (i >= 320 * 320) return;
    int j = i & 7;
    int lane = (i >> 3) & 63;
    int r = i >> 9;
    int kb = r % 10;
    int t = r / 10;
    int n = t * 16 + (lane & 15);
    int k = kb * 32 + ((lane >> 4) << 3) + j;
    float v = (n < 160) ? w1[n * 320 + k] : wt[(n - 160) * 320 + k];
    dst[i] = f2bf(v);
}

__global__ void pack_w2(const float* __restrict__ w2, unsigned short* __restrict__ dst) {
    int i = blockIdx.x * 256 + threadIdx.x;
    if (i >= 160 * 160) return;
    int j = i & 7;
    int lane = (i >> 3) & 63;
    int r = i >> 9;
    int kb = r % 5;
    int t = r / 5;
    int n = t * 16 + (lane & 15);
    int k = kb * 32 + ((lane >> 4) << 3) + j;
    dst[i] = f2bf(w2[n * 160 + k]);
}

// 32 rows/block, 128 threads (2 waves), 21.5 KB LDS -> 7 blocks/CU.
// GEMM1 n-split: wave0 -> h1 cols (0..160), wave1 -> ht cols (160..320) => GN1 stats wave-local.
// GEMM2 m-split: wave w -> rows 16w..16w+16, all 160 cols => GN2 stats wave-local.
__global__ __launch_bounds__(128, 3) void fused_kernel(
    const float* __restrict__ actors, const float* __restrict__ paths,
    const float* __restrict__ Z_act, const float* __restrict__ Z_pat,
    const int* __restrict__ u,
    const unsigned short* __restrict__ pB1, const unsigned short* __restrict__ pB2,
    const float* __restrict__ g1w, const float* __restrict__ g1b,
    const float* __restrict__ g2w, const float* __restrict__ g2b,
    const float* __restrict__ wh, const float* __restrict__ bh,
    float* __restrict__ out)
{
    // LDS: [0, 20992) lX (32 x XP bf16); aliased after GEMM1:
    //   [0,10752) lH1 (32 x HP bf16), [10752,21504) lHT (32 x HP bf16)
    __shared__ __align__(16) char smem[21504];
    unsigned short* lX  = (unsigned short*)smem;
    unsigned short* lH1 = (unsigned short*)smem;
    unsigned short* lHT = (unsigned short*)(smem + 10752);

    const int tid  = threadIdx.x;
    const int wave = tid >> 6;
    const int lane = tid & 63;
    const int quad = lane >> 4;
    const int l15  = lane & 15;
    const int row0 = blockIdx.x * 32;

    // ================= staging: phase-split loads for MLP =================
    float4 vD[10], vG[10];
    int uv[10];
    #pragma unroll
    for (int i = 0; i < 10; i++) {           // phase A: direct loads + u loads
        int f = i * 128 + tid;
        int r = f / 40, q = f - r * 40;
        const float* src = (q < 32) ? (paths + (size_t)(row0 + r) * 128 + q * 4)
                                    : (Z_pat + (size_t)(row0 + r) * 32 + (q - 32) * 4);
        vD[i] = *(const float4*)src;
        uv[i] = u[row0 + r];
    }
    #pragma unroll
    for (int i = 0; i < 10; i++) {           // phase B: dependent gather loads
        int f = i * 128 + tid;
        int q = f % 40;
        int un = uv[i];
        const float* src = (q < 32) ? (actors + (size_t)un * 128 + q * 4)
                                    : (Z_act + (size_t)un * 32 + (q - 32) * 4);
        vG[i] = *(const float4*)src;
    }
    #pragma unroll
    for (int i = 0; i < 10; i++) {           // phase C: convert + LDS write
        int f = i * 128 + tid;
        int r = f / 40, q = f - r * 40;
        ushort4 sv;
        sv.x = f2bf(vD[i].x); sv.y = f2bf(vD[i].y); sv.z = f2bf(vD[i].z); sv.w = f2bf(vD[i].w);
        *(ushort4*)(lX + r * XP + q * 4) = sv;
    }
    #pragma unroll
    for (int i = 0; i < 10; i++) {
        int f = i * 128 + tid;
        int r = f / 40, q = f - r * 40;
        ushort4 sv;
        sv.x = f2bf(vG[i].x); sv.y = f2bf(vG[i].y); sv.z = f2bf(vG[i].z); sv.w = f2bf(vG[i].w);
        *(ushort4*)(lX + r * XP + 160 + q * 4) = sv;
    }

    // prefetch GEMM1 B fragments kb=0 (L2 loads, independent of LDS)
    short8 bC[10], bN[10];
    #pragma unroll
    for (int ti = 0; ti < 10; ti++) {
        int t = wave * 10 + ti;
        bC[ti] = *(const short8*)(pB1 + ((size_t)(t * 10 + 0) * 64 + lane) * 8);
    }
    __syncthreads();

    // ================= GEMM1: C[32 x 320] = X @ [w1;wt]^T =================
    floatx4 fzero = {0.f, 0.f, 0.f, 0.f};
    floatx4 acc[2][10];
    #pragma unroll
    for (int i = 0; i < 2; i++)
        #pragma unroll
        for (int j = 0; j < 10; j++) acc[i][j] = fzero;

    #pragma unroll
    for (int kb = 0; kb < 10; kb++) {
        short8 a[2];
        #pragma unroll
        for (int mt = 0; mt < 2; mt++)
            a[mt] = *(const short8*)(lX + (mt * 16 + l15) * XP + kb * 32 + quad * 8);
        if (kb < 9) {
            #pragma unroll
            for (int ti = 0; ti < 10; ti++) {
                int t = wave * 10 + ti;
                bN[ti] = *(const short8*)(pB1 + ((size_t)(t * 10 + kb + 1) * 64 + lane) * 8);
            }
        }
        #pragma unroll
        for (int ti = 0; ti < 10; ti++)
            #pragma unroll
            for (int mt = 0; mt < 2; mt++)
                acc[mt][ti] = __builtin_amdgcn_mfma_f32_16x16x32_bf16(a[mt], bC[ti], acc[mt][ti], 0, 0, 0);
        #pragma unroll
        for (int ti = 0; ti < 10; ti++) bC[ti] = bN[ti];
    }
    __syncthreads();   // lX reads done; safe to overwrite with lH1/lHT

    if (wave == 0) {
        // ---- GN1 stats (wave-local): row m = mt*16 + quad*4 + r over 160 cols ----
        float s[8], q2[8];
        #pragma unroll
        for (int mt = 0; mt < 2; mt++)
            #pragma unroll
            for (int r = 0; r < 4; r++) {
                float sv = 0.f, qv = 0.f;
                #pragma unroll
                for (int ti = 0; ti < 10; ti++) {
                    float v = acc[mt][ti][r];
                    sv += v; qv += v * v;
                }
                s[mt * 4 + r] = sv; q2[mt * 4 + r] = qv;
            }
        #pragma unroll
        for (int off = 1; off <= 8; off <<= 1)
            #pragma unroll
            for (int k = 0; k < 8; k++) {
                s[k]  += __shfl_xor(s[k],  off, 64);
                q2[k] += __shfl_xor(q2[k], off, 64);
            }
        float gw[10], gb[10];
        #pragma unroll
        for (int ti = 0; ti < 10; ti++) {
            int n = ti * 16 + l15;
            gw[ti] = g1w[n]; gb[ti] = g1b[n];
        }
        // ---- GN1 apply + ReLU + write h1 ----
        #pragma unroll
        for (int mt = 0; mt < 2; mt++)
            #pragma unroll
            for (int r = 0; r < 4; r++) {
                float mu = s[mt * 4 + r] * (1.f / 160.f);
                float var = q2[mt * 4 + r] * (1.f / 160.f) - mu * mu;
                float rs = rsqrtf(var + 1e-5f);
                int m = mt * 16 + quad * 4 + r;
                #pragma unroll
                for (int ti = 0; ti < 10; ti++) {
                    float v = (acc[mt][ti][r] - mu) * rs * gw[ti] + gb[ti];
                    v = fmaxf(v, 0.f);
                    lH1[m * HP + ti * 16 + l15] = f2bf(v);
                }
            }
    } else {
        // ---- park ht (cols 160..320) ----
        #pragma unroll
        for (int mt = 0; mt < 2; mt++)
            #pragma unroll
            for (int ti = 0; ti < 10; ti++)
                #pragma unroll
                for (int r = 0; r < 4; r++) {
                    int m = mt * 16 + quad * 4 + r;
                    lHT[m * HP + ti * 16 + l15] = f2bf(acc[mt][ti][r]);
                }
    }

    // prefetch GEMM2 B fragments kb=0 (both waves read same fragments)
    short8 b2C[10], b2N[10];
    #pragma unroll
    for (int ti = 0; ti < 10; ti++)
        b2C[ti] = *(const short8*)(pB2 + ((size_t)(ti * 5 + 0) * 64 + lane) * 8);
    __syncthreads();

    // ================= GEMM2 (m-split): rows w*16..w*16+16, all 160 cols =================
    floatx4 acc2[10];
    #pragma unroll
    for (int j = 0; j < 10; j++) acc2[j] = fzero;

    #pragma unroll
    for (int kb = 0; kb < 5; kb++) {
        short8 a = *(const short8*)(lH1 + (wave * 16 + l15) * HP + kb * 32 + quad * 8);
        if (kb < 4) {
            #pragma unroll
            for (int ti = 0; ti < 10; ti++)
                b2N[ti] = *(const short8*)(pB2 + ((size_t)(ti * 5 + kb + 1) * 64 + lane) * 8);
        }
        #pragma unroll
        for (int ti = 0; ti < 10; ti++)
            acc2[ti] = __builtin_amdgcn_mfma_f32_16x16x32_bf16(a, b2C[ti], acc2[ti], 0, 0, 0);
        #pragma unroll
        for (int ti = 0; ti < 10; ti++) b2C[ti] = b2N[ti];
    }

    // ================= GN2 stats (wave-local) + skip + ReLU + head dot =================
    {
        float s[4], q2[4];
        #pragma unroll
        for (int r = 0; r < 4; r++) {
            float sv = 0.f, qv = 0.f;
            #pragma unroll
            for (int ti = 0; ti < 10; ti++) {
                float v = acc2[ti][r];
                sv += v; qv += v * v;
            }
            s[r] = sv; q2[r] = qv;
        }
        #pragma unroll
        for (int off = 1; off <= 8; off <<= 1)
            #pragma unroll
            for (int r = 0; r < 4; r++) {
                s[r]  += __shfl_xor(s[r],  off, 64);
                q2[r] += __shfl_xor(q2[r], off, 64);
            }
        float g2wv[10], g2bv[10], whv[10];
        #pragma unroll
        for (int ti = 0; ti < 10; ti++) {
            int n = ti * 16 + l15;
            g2wv[ti] = g2w[n]; g2bv[ti] = g2b[n]; whv[ti] = wh[n];
        }
        float dp[4];
        #pragma unroll
        for (int r = 0; r < 4; r++) {
            float mu = s[r] * (1.f / 160.f);
            float var = q2[r] * (1.f / 160.f) - mu * mu;
            float rs = rsqrtf(var + 1e-5f);
            int m = wave * 16 + quad * 4 + r;
            float d = 0.f;
            #pragma unroll
            for (int ti = 0; ti < 10; ti++) {
                float v = (acc2[ti][r] - mu) * rs * g2wv[ti] + g2bv[ti];
                v += bf2f(lHT[m * HP + ti * 16 + l15]);
                v = fmaxf(v, 0.f);
                d += v * whv[ti];
            }
            dp[r] = d;
        }
        #pragma unroll
        for (int off = 1; off <= 8; off <<= 1)
            #pragma unroll
            for (int r = 0; r < 4; r++) dp[r] += __shfl_xor(dp[r], off, 64);
        if (l15 == 0) {
            float bh0 = bh[0];
            #pragma unroll
            for (int r = 0; r < 4; r++)
                out[row0 + wave * 16 + quad * 4 + r] = dp[r] + bh0;
        }
    }
}

extern "C" void kernel_launch(void* const* d_in, const int* in_sizes, int n_in,
                              void* d_out, int out_size, void* d_ws, size_t ws_size,
                              hipStream_t stream) {
    const float* actors = (const float*)d_in[0];
    const float* paths  = (const float*)d_in[1];
    const float* Z_act  = (const float*)d_in[2];
    const float* Z_pat  = (const float*)d_in[3];
    const int*   u      = (const int*)d_in[4];
    const float* w1     = (const float*)d_in[5];
    const float* w2     = (const float*)d_in[6];
    const float* wt     = (const float*)d_in[7];
    const float* g1w    = (const float*)d_in[8];
    const float* g1b    = (const float*)d_in[9];
    const float* g2w    = (const float*)d_in[10];
    const float* g2b    = (const float*)d_in[11];
    const float* wh     = (const float*)d_in[12];
    const float* bh     = (const float*)d_in[13];
    float* out = (float*)d_out;

    unsigned short* pB1 = (unsigned short*)d_ws;
    unsigned short* pB2 = pB1 + 320 * 320;

    hipLaunchKernelGGL(pack_wc, dim3(400), dim3(256), 0, stream, w1, wt, pB1);
    hipLaunchKernelGGL(pack_w2, dim3(100), dim3(256), 0, stream, w2, pB2);
    hipLaunchKernelGGL(fused_kernel, dim3(400000 / 32), dim3(128), 0, stream,
                       actors, paths, Z_act, Z_pat, u, pB1, pB2,
                       g1w, g1b, g2w, g2b, wh, bh, out);
}